// Round 2
// baseline (92.220 us; speedup 1.0000x reference)
//
#include <hip/hip_runtime.h>

// CCM: causal 3x3 complex multi-frame filter.
// out[b,f,t,:] = sum_{i,j} (Hr+i*Hi)[b,i,j,t,f] * x[b, f+j-1, t+i-2, :]
// Hr = a0 - 0.5*(a1+a2); Hi = (sqrt(3)/2)*(a1-a2); a_k = m[b, 9k+3i+j, t, f]

constexpr int B = 8, C = 27, T = 1000, F = 257;
constexpr int TCH = 4;           // t-chunk per thread (4 -> 2x waves vs 8)
constexpr int NT = T / TCH;      // 250

__global__ __launch_bounds__(256, 4)   // cap VGPR at 128 -> 4 waves/EU
void ccm_kernel(const float* __restrict__ m,
                const float* __restrict__ x,
                float* __restrict__ out) {
    const int tid = blockIdx.x * blockDim.x + threadIdx.x;
    const int total = B * NT * F;
    if (tid >= total) return;

    const int f   = tid % F;
    const int rem = tid / F;
    const int tc  = rem % NT;
    const int b   = rem / NT;
    const int t0  = tc * TCH;

    const float SQ3_2 = 0.8660254037844386f;

    const bool vf0 = (f >= 1);       // f-1 valid
    const bool vf2 = (f + 1 < F);    // f+1 valid

    const float* xb = x + (size_t)b * F * T * 2;

    // sliding window over time taps: row p=0 -> t-2, p=1 -> t-1, p=2 -> t
    float wr[3][3], wi[3][3];

    auto loadrow = [&](int tt, int p) {
        #pragma unroll
        for (int j = 0; j < 3; ++j) {
            const int ff = f + j - 1;
            const bool okf = (j == 0) ? vf0 : ((j == 2) ? vf2 : true);
            if (tt >= 0 && okf) {
                const float2 val = *reinterpret_cast<const float2*>(
                    xb + ((size_t)ff * T + tt) * 2);
                wr[p][j] = val.x;
                wi[p][j] = val.y;
            } else {
                wr[p][j] = 0.0f;
                wi[p][j] = 0.0f;
            }
        }
    };

    loadrow(t0 - 2, 0);
    loadrow(t0 - 1, 1);

    const float* mb = m + ((size_t)b * C * T + t0) * F + f;
    constexpr size_t CSTRIDE = (size_t)T * F;   // per-channel stride in m

    float2 res[TCH];

    #pragma unroll
    for (int u = 0; u < TCH; ++u) {
        const int t = t0 + u;
        loadrow(t, 2);                           // newest row (t >= 0 always)
        const float* mp = mb + (size_t)u * F;

        // Batch ALL 27 m-loads of this t-step into registers (static
        // indexing -> VGPRs, one clustered issue group, single waitcnt).
        float a0v[9], a1v[9], a2v[9];
        #pragma unroll
        for (int n = 0; n < 9; ++n) {
            a0v[n] = mp[(size_t)(0 * 9 + n) * CSTRIDE];
            a1v[n] = mp[(size_t)(1 * 9 + n) * CSTRIDE];
            a2v[n] = mp[(size_t)(2 * 9 + n) * CSTRIDE];
        }

        float accr = 0.0f, acci = 0.0f;
        #pragma unroll
        for (int i = 0; i < 3; ++i) {
            #pragma unroll
            for (int j = 0; j < 3; ++j) {
                const int n = i * 3 + j;
                const float hr = a0v[n] - 0.5f * (a1v[n] + a2v[n]);
                const float hi = SQ3_2 * (a1v[n] - a2v[n]);
                const float xr = wr[i][j], xi = wi[i][j];
                accr += hr * xr - hi * xi;
                acci += hr * xi + hi * xr;
            }
        }
        res[u] = make_float2(accr, acci);

        // shift window
        #pragma unroll
        for (int j = 0; j < 3; ++j) {
            wr[0][j] = wr[1][j]; wi[0][j] = wi[1][j];
            wr[1][j] = wr[2][j]; wi[1][j] = wi[2][j];
        }
    }

    // contiguous 32B write: out[b, f, t0..t0+3, 0..1]
    float* op = out + ((size_t)(b * F + f) * T + t0) * 2;
    #pragma unroll
    for (int u = 0; u < TCH / 2; ++u) {
        reinterpret_cast<float4*>(op)[u] =
            make_float4(res[2 * u].x, res[2 * u].y,
                        res[2 * u + 1].x, res[2 * u + 1].y);
    }
}

extern "C" void kernel_launch(void* const* d_in, const int* in_sizes, int n_in,
                              void* d_out, int out_size, void* d_ws, size_t ws_size,
                              hipStream_t stream) {
    const float* m = (const float*)d_in[0];
    const float* x = (const float*)d_in[1];
    // d_in[2] = v is a fixed compile-time constant per the reference.
    float* out = (float*)d_out;

    const int total = B * NT * F;          // 514,000 threads
    const int block = 256;
    const int grid = (total + block - 1) / block;
    ccm_kernel<<<grid, block, 0, stream>>>(m, x, out);
}

// Round 3
// 68.052 us; speedup vs baseline: 1.3551x; 1.3551x over previous
//
#include <hip/hip_runtime.h>

// CCM: causal 3x3 complex multi-frame filter.
// out[b,f,t,:] = sum_{i,j} (Hr+i*Hi)[b,i,j,t,f] * x[b, f+j-1, t+i-2, :]
// Hr = a0 - 0.5*(a1+a2); Hi = (sqrt(3)/2)*(a1-a2); a_k = m[b, 9k+3i+j, t, f]
//
// Block = one (b, t-chunk) tile, 320 threads (5 waves), lane = f.
// x window staged to LDS once (coalesced), m streamed coalesced from global.

constexpr int B = 8, C = 27, T = 1000, F = 257;
constexpr int TCH = 8;               // t per thread -> full 64B line writes
constexpr int NT  = T / TCH;         // 125
constexpr int BLK = 320;             // 5 waves; covers f = 0..256 (+63 idle)
constexpr int TROW  = 10;            // staged t range: t0-2 .. t0+7
constexpr int ROWSU = 259;           // rows used: f = -1 .. 257  (row = f+1)
constexpr int RP    = 11;            // row pitch (odd -> conflict-free reads)
constexpr int PLANE = 260 * RP;      // dwords per plane (re / im)

__global__ __launch_bounds__(BLK, 4)   // VGPR <= 128
void ccm_kernel(const float* __restrict__ m,
                const float* __restrict__ x,
                float* __restrict__ out) {
    __shared__ float xs[2 * PLANE];    // ~22.9 KB

    const int bid = blockIdx.x;
    const int tc  = bid % NT;
    const int b   = bid / NT;
    const int t0  = tc * TCH;
    const int tx  = threadIdx.x;

    const float* xb = x + (size_t)b * F * T * 2;

    // ---- stage x window into LDS (re/im planes), coalesced-ish ----
    for (int p = tx; p < ROWSU * TROW; p += BLK) {
        const int row = p / TROW;          // 0..258
        const int tt  = p - row * TROW;    // 0..9
        const int f   = row - 1;           // -1..257
        const int t   = t0 - 2 + tt;
        float re = 0.f, im = 0.f;
        if (f >= 0 && f < F && t >= 0) {
            const float2 v = *reinterpret_cast<const float2*>(
                xb + ((size_t)f * T + t) * 2);
            re = v.x; im = v.y;
        }
        xs[row * RP + tt]         = re;
        xs[PLANE + row * RP + tt] = im;
    }
    __syncthreads();          // only barrier; threads may exit after

    if (tx >= F) return;
    const int f = tx;

    const float SQ3_2 = 0.8660254037844386f;

    // sliding window: wr[i][j] = Re x[t+i-2, f+j-1], row index = f+j
    float wr[3][3], wi[3][3];
    #pragma unroll
    for (int p = 0; p < 2; ++p) {
        #pragma unroll
        for (int j = 0; j < 3; ++j) {
            wr[p][j] = xs[(f + j) * RP + p];
            wi[p][j] = xs[PLANE + (f + j) * RP + p];
        }
    }

    // m base: block-uniform part + lane f; per-load offsets are constants
    const float* mb = m + ((size_t)b * C * T + t0) * F + f;
    constexpr size_t CS = (size_t)T * F;   // channel stride

    float2 res[TCH];

    #pragma unroll
    for (int u = 0; u < TCH; ++u) {
        #pragma unroll
        for (int j = 0; j < 3; ++j) {
            wr[2][j] = xs[(f + j) * RP + (u + 2)];
            wi[2][j] = xs[PLANE + (f + j) * RP + (u + 2)];
        }

        float a0v[9], a1v[9], a2v[9];
        #pragma unroll
        for (int n = 0; n < 9; ++n) {
            a0v[n] = mb[(size_t)(0 * 9 + n) * CS + (size_t)u * F];
            a1v[n] = mb[(size_t)(1 * 9 + n) * CS + (size_t)u * F];
            a2v[n] = mb[(size_t)(2 * 9 + n) * CS + (size_t)u * F];
        }

        float accr = 0.f, acci = 0.f;
        #pragma unroll
        for (int i = 0; i < 3; ++i) {
            #pragma unroll
            for (int j = 0; j < 3; ++j) {
                const int n = i * 3 + j;
                const float hr = a0v[n] - 0.5f * (a1v[n] + a2v[n]);
                const float hi = SQ3_2 * (a1v[n] - a2v[n]);
                accr += hr * wr[i][j] - hi * wi[i][j];
                acci += hr * wi[i][j] + hi * wr[i][j];
            }
        }
        res[u] = make_float2(accr, acci);

        #pragma unroll
        for (int j = 0; j < 3; ++j) {
            wr[0][j] = wr[1][j]; wi[0][j] = wi[1][j];
            wr[1][j] = wr[2][j]; wi[1][j] = wi[2][j];
        }
    }

    // contiguous aligned 64B write: out[b, f, t0..t0+7, 0..1]
    float* op = out + ((size_t)(b * F + f) * T + t0) * 2;
    #pragma unroll
    for (int u = 0; u < TCH / 2; ++u) {
        reinterpret_cast<float4*>(op)[u] =
            make_float4(res[2 * u].x, res[2 * u].y,
                        res[2 * u + 1].x, res[2 * u + 1].y);
    }
}

extern "C" void kernel_launch(void* const* d_in, const int* in_sizes, int n_in,
                              void* d_out, int out_size, void* d_ws, size_t ws_size,
                              hipStream_t stream) {
    const float* m = (const float*)d_in[0];
    const float* x = (const float*)d_in[1];
    // d_in[2] = v is a fixed compile-time constant per the reference.
    float* out = (float*)d_out;

    const int grid = B * NT;               // 1000 blocks
    ccm_kernel<<<grid, BLK, 0, stream>>>(m, x, out);
}

// Round 4
// 59.264 us; speedup vs baseline: 1.5561x; 1.1483x over previous
//
#include <hip/hip_runtime.h>

// CCM: causal 3x3 complex multi-frame filter.
// out[b,f,t,:] = sum_{i,j} (Hr+i*Hi)[b,i,j,t,f] * x[b, f+j-1, t+i-2, :]
// Hr = a0 - 0.5*(a1+a2); Hi = (sqrt(3)/2)*(a1-a2); a_k = m[b, 9k+3i+j, t, f]
//
// Block = one (b, t-chunk) tile, 320 threads, lane = f.
// x window staged in LDS; m streamed with explicit double-buffered
// 27-load register batches so one full t-step of loads is always in flight.

constexpr int B = 8, C = 27, T = 1000, F = 257;
constexpr int TCH = 4;               // t per block tile
constexpr int NT  = T / TCH;         // 250 -> 2000 blocks
constexpr int BLK = 320;             // 5 waves; lane = f (0..256)
constexpr int TROW  = TCH + 2;       // staged t range: t0-2 .. t0+TCH-1
constexpr int ROWSU = 259;           // rows used: f = -1..257 (row = f+1)
constexpr int RP    = 7;             // odd row pitch -> conflict-free
constexpr int PLANE = 260 * RP;      // dwords per plane

__global__ __launch_bounds__(BLK, 4)   // VGPR cap 128 -> 4 waves/EU
void ccm_kernel(const float* __restrict__ m,
                const float* __restrict__ x,
                float* __restrict__ out) {
    __shared__ float xs[2 * PLANE];    // 14.6 KB

    const int bid = blockIdx.x;
    const int tc  = bid % NT;
    const int b   = bid / NT;
    const int t0  = tc * TCH;
    const int tx  = threadIdx.x;

    const float* xb = x + (size_t)b * F * T * 2;

    // ---- stage x window into LDS (re/im planes) ----
    for (int p = tx; p < ROWSU * TROW; p += BLK) {
        const int row = p / TROW;          // 0..258
        const int tt  = p - row * TROW;    // 0..TROW-1
        const int f   = row - 1;           // -1..257
        const int t   = t0 - 2 + tt;
        float re = 0.f, im = 0.f;
        if (f >= 0 && f < F && t >= 0) {
            const float2 v = *reinterpret_cast<const float2*>(
                xb + ((size_t)f * T + t) * 2);
            re = v.x; im = v.y;
        }
        xs[row * RP + tt]         = re;
        xs[PLANE + row * RP + tt] = im;
    }
    __syncthreads();

    if (tx >= F) return;
    const int f = tx;

    const float SQ3_2 = 0.8660254037844386f;
    constexpr size_t CS = (size_t)T * F;               // m channel stride
    const float* mb = m + ((size_t)b * C * T + t0) * F; // block-uniform base

    // sliding window: wr[i][j] = Re x[t+i-2, f+j-1]; LDS row = f+j
    float wr[3][3], wi[3][3];
    #pragma unroll
    for (int p = 0; p < 2; ++p) {
        #pragma unroll
        for (int j = 0; j < 3; ++j) {
            wr[p][j] = xs[(f + j) * RP + p];
            wi[p][j] = xs[PLANE + (f + j) * RP + p];
        }
    }

    float2 res[TCH];

// 27-load batch for t-step U into named register array DST (static idx)
#define LOADM(DST, U)                                                     \
    {                                                                     \
        _Pragma("unroll")                                                 \
        for (int n = 0; n < 27; ++n)                                      \
            DST[n] = mb[(size_t)n * CS + (size_t)(U) * F + f];            \
    }

// consume batch AV for t-step U: refresh window row 2, 3x3 complex MAC
#define STEP(AV, U)                                                       \
    {                                                                     \
        _Pragma("unroll")                                                 \
        for (int j = 0; j < 3; ++j) {                                     \
            wr[2][j] = xs[(f + j) * RP + ((U) + 2)];                      \
            wi[2][j] = xs[PLANE + (f + j) * RP + ((U) + 2)];              \
        }                                                                 \
        float accr = 0.f, acci = 0.f;                                     \
        _Pragma("unroll")                                                 \
        for (int i = 0; i < 3; ++i) {                                     \
            _Pragma("unroll")                                             \
            for (int j = 0; j < 3; ++j) {                                 \
                const int n = i * 3 + j;                                  \
                const float hr = AV[n] - 0.5f * (AV[n + 9] + AV[n + 18]); \
                const float hi = SQ3_2 * (AV[n + 9] - AV[n + 18]);        \
                accr += hr * wr[i][j] - hi * wi[i][j];                    \
                acci += hr * wi[i][j] + hi * wr[i][j];                    \
            }                                                             \
        }                                                                 \
        res[U] = make_float2(accr, acci);                                 \
        _Pragma("unroll")                                                 \
        for (int j = 0; j < 3; ++j) {                                     \
            wr[0][j] = wr[1][j]; wi[0][j] = wi[1][j];                     \
            wr[1][j] = wr[2][j]; wi[1][j] = wi[2][j];                     \
        }                                                                 \
    }

    float Am[27], Bm[27];
    LOADM(Am, 0);                 // prologue
    LOADM(Bm, 1);  STEP(Am, 0);   // step u: next batch in flight
    LOADM(Am, 2);  STEP(Bm, 1);
    LOADM(Bm, 3);  STEP(Am, 2);
                   STEP(Bm, 3);

#undef LOADM
#undef STEP

    // contiguous aligned 32B write: out[b, f, t0..t0+3, 0..1]
    float* op = out + ((size_t)(b * F + f) * T + t0) * 2;
    #pragma unroll
    for (int u = 0; u < TCH / 2; ++u) {
        reinterpret_cast<float4*>(op)[u] =
            make_float4(res[2 * u].x, res[2 * u].y,
                        res[2 * u + 1].x, res[2 * u + 1].y);
    }
}

extern "C" void kernel_launch(void* const* d_in, const int* in_sizes, int n_in,
                              void* d_out, int out_size, void* d_ws, size_t ws_size,
                              hipStream_t stream) {
    const float* m = (const float*)d_in[0];
    const float* x = (const float*)d_in[1];
    // d_in[2] = v is a fixed compile-time constant per the reference.
    float* out = (float*)d_out;

    const int grid = B * NT;               // 2000 blocks
    ccm_kernel<<<grid, BLK, 0, stream>>>(m, x, out);
}